// Round 6
// baseline (455.212 us; speedup 1.0000x reference)
//
#include <hip/hip_runtime.h>
#include <hip/hip_bf16.h>
#include <math.h>

#define DIM 384
#define HEADS 6
#define HIDDEN 1536
#define NTOK 2744   // 14*14*14
#define BATCH 2
#define MTOT (BATCH * NTOK)   // 5488
#define KSPLIT 3
#define NQT 22      // ceil(2744/128)

typedef __bf16 bf16x8 __attribute__((ext_vector_type(8)));
typedef __bf16 bf16x4 __attribute__((ext_vector_type(4)));
typedef float  f32x4  __attribute__((ext_vector_type(4)));

// async global->LDS, 16B per lane; LDS dest = uniform base + lane*16
__device__ __forceinline__ void gll16(const void* g, void* l) {
    __builtin_amdgcn_global_load_lds(
        (const __attribute__((address_space(1))) unsigned int*)g,
        (__attribute__((address_space(3))) unsigned int*)l, 16, 0, 0);
}

// ---------------------------------------------------------------------------
// Kernel 1: fused depthwise conv3d (+residual, NCDHW -> t[token,C] fp32)
// and weight fp32->bf16 conversion (tail blocks).
// conv: blocks [0, 8448) = (11 nblk) x (384 c) x (2 b); wcvt: 1728 blocks.
// ---------------------------------------------------------------------------
__global__ void conv_wcvt_kernel(const float* __restrict__ x,
                                 const float* __restrict__ cw,
                                 float* __restrict__ t,
                                 const float* __restrict__ w0, const float* __restrict__ w1,
                                 const float* __restrict__ w2, const float* __restrict__ w3,
                                 __bf16* o0, __bf16* o1, __bf16* o2, __bf16* o3) {
    int bid = blockIdx.x;
    if (bid >= 8448) {   // ---- weight conversion ----
        int i = (bid - 8448) * 256 + threadIdx.x;   // float4 index
        const float* s; __bf16* d; int off;
        if (i < 110592)      { s = w0; d = o0; off = i; }
        else if (i < 147456) { s = w1; d = o1; off = i - 110592; }
        else if (i < 294912) { s = w2; d = o2; off = i - 147456; }
        else                 { s = w3; d = o3; off = i - 294912; }
        float4 v = ((const float4*)s)[off];
        bf16x4 bb = { (__bf16)v.x, (__bf16)v.y, (__bf16)v.z, (__bf16)v.w };
        *(bf16x4*)(d + (size_t)off * 4) = bb;
        return;
    }
    // ---- conv ----
    int nb = bid % 11, rest = bid / 11;
    int c = rest % 384, b = rest / 384;
    int n = nb * 256 + threadIdx.x;
    if (n >= NTOK) return;
    int d = n / 196, r = n % 196, h = r / 14, w = r % 14;
    const float* xp = x + ((size_t)b * DIM + c) * NTOK;
    const float* wp = cw + c * 27;
    float acc = xp[n];   // residual (conv_b cancels in reference)
    #pragma unroll
    for (int kd = 0; kd < 3; kd++) {
        int dd = d + kd - 1;
        if (dd < 0 || dd >= 14) continue;
        #pragma unroll
        for (int kh = 0; kh < 3; kh++) {
            int hh = h + kh - 1;
            if (hh < 0 || hh >= 14) continue;
            #pragma unroll
            for (int kw = 0; kw < 3; kw++) {
                int ww = w + kw - 1;
                if (ww < 0 || ww >= 14) continue;
                acc += wp[kd * 9 + kh * 3 + kw] * xp[(dd * 14 + hh) * 14 + ww];
            }
        }
    }
    t[((size_t)(b * NTOK + n)) * DIM + c] = acc;
}

// ---------------------------------------------------------------------------
// Kernel 2: LayerNorm fp32 in -> bf16 out. One wave per token.
// ---------------------------------------------------------------------------
__global__ void ln_kernel(const float* __restrict__ in, __bf16* __restrict__ out,
                          const float* __restrict__ w, const float* __restrict__ b) {
    int wid = threadIdx.x >> 6, lane = threadIdx.x & 63;
    int token = blockIdx.x * 4 + wid;
    const float* row = in + (size_t)token * DIM;
    float v[6];
    float s = 0.f, s2 = 0.f;
    #pragma unroll
    for (int i = 0; i < 6; i++) {
        v[i] = row[lane + 64 * i];
        s += v[i];
        s2 += v[i] * v[i];
    }
    #pragma unroll
    for (int m = 1; m < 64; m <<= 1) {
        s += __shfl_xor(s, m);
        s2 += __shfl_xor(s2, m);
    }
    float mu = s * (1.f / DIM);
    float var = s2 * (1.f / DIM) - mu * mu;
    float rstd = rsqrtf(var + 1e-5f);
    __bf16* orow = out + (size_t)token * DIM;
    #pragma unroll
    for (int i = 0; i < 6; i++) {
        int c = lane + 64 * i;
        orow[c] = (__bf16)((v[i] - mu) * rstd * w[c] + b[c]);
    }
}

#define F_GELU  1
#define F_RESID 2
#define F_BF16  4
#define F_QKV   8
#define F_TRANS 16

// ---------------------------------------------------------------------------
// Kernel 3a: bf16 MFMA GEMM, tile 128x64x64 (proj, fc2). Dbuf async staging
// + XOR chunk swizzle (bank-optimal b128 frag reads).
// ---------------------------------------------------------------------------
__global__ __launch_bounds__(256) void gemm_mfma(
    const __bf16* __restrict__ A, const __bf16* __restrict__ B,
    const float* __restrict__ bias, const float* __restrict__ resid,
    void* __restrict__ out, int M, int N, int K, int flags) {
    __shared__ __bf16 As[2][128][64];   // 32 KB
    __shared__ __bf16 Bs[2][64][64];    // 16 KB
    int tid = threadIdx.x, lane = tid & 63;
    int wid = tid >> 6;
    int quad = lane >> 4, l16 = lane & 15;
    int wm = wid & 1, wn = wid >> 1;
    int m0 = blockIdx.y * 128, n0 = blockIdx.x * 64;
    int x7 = l16 & 7;

    auto stage = [&](int k0, int buf) {
        #pragma unroll
        for (int i = 0; i < 4; i++) {
            int c = i * 256 + tid;
            int row = c >> 3, cc = (c & 7) ^ (row & 7);
            int gm = m0 + row; if (gm > M - 1) gm = M - 1;
            gll16(A + (size_t)gm * K + k0 + cc * 8, &As[buf][0][0] + (size_t)c * 8);
        }
        #pragma unroll
        for (int i = 0; i < 2; i++) {
            int c = i * 256 + tid;
            int row = c >> 3, cc = (c & 7) ^ (row & 7);
            gll16(B + (size_t)(n0 + row) * K + k0 + cc * 8, &Bs[buf][0][0] + (size_t)c * 8);
        }
    };

    f32x4 acc[4][2] = {};
    int nk = K >> 6;
    stage(0, 0);
    __syncthreads();
    for (int ki = 0; ki < nk; ki++) {
        int cur = ki & 1;
        if (ki + 1 < nk) stage((ki + 1) << 6, cur ^ 1);
        #pragma unroll
        for (int s = 0; s < 2; s++) {
            bf16x8 a[4], b[2];
            #pragma unroll
            for (int i = 0; i < 4; i++)
                a[i] = *(bf16x8*)&As[cur][wm * 64 + i * 16 + l16][(((s * 4 + quad) ^ x7)) * 8];
            #pragma unroll
            for (int j = 0; j < 2; j++)
                b[j] = *(bf16x8*)&Bs[cur][wn * 32 + j * 16 + l16][(((s * 4 + quad) ^ x7)) * 8];
            #pragma unroll
            for (int i = 0; i < 4; i++)
                #pragma unroll
                for (int j = 0; j < 2; j++)
                    acc[i][j] = __builtin_amdgcn_mfma_f32_16x16x32_bf16(a[i], b[j], acc[i][j], 0, 0, 0);
        }
        __syncthreads();
    }

    int colb = n0 + wn * 32;
    #pragma unroll
    for (int j = 0; j < 2; j++) {
        int col = colb + j * 16 + l16;
        float bv = bias ? bias[col] : 0.f;
        #pragma unroll
        for (int i = 0; i < 4; i++) {
            int row0 = m0 + wm * 64 + i * 16 + quad * 4;
            if (row0 >= M) continue;
            float v4[4];
            #pragma unroll
            for (int r = 0; r < 4; r++) {
                float v = acc[i][j][r] + bv;
                if (flags & F_GELU) v = 0.5f * v * (1.f + erff(v * 0.70710678f));
                if (flags & F_RESID) v += resid[(size_t)(row0 + r) * N + col];
                v4[r] = v;
            }
            if (flags & F_TRANS) {
                int b2 = row0 / NTOK, n2 = row0 - b2 * NTOK;
                float4 pk = { v4[0], v4[1], v4[2], v4[3] };
                *(float4*)((float*)out + ((size_t)(b2 * N + col)) * NTOK + n2) = pk;
            } else if (flags & F_BF16) {
                #pragma unroll
                for (int r = 0; r < 4; r++)
                    ((__bf16*)out)[(size_t)(row0 + r) * N + col] = (__bf16)v4[r];
            } else {
                #pragma unroll
                for (int r = 0; r < 4; r++)
                    ((float*)out)[(size_t)(row0 + r) * N + col] = v4[r];
            }
        }
    }
}

// ---------------------------------------------------------------------------
// Kernel 3b: bf16 MFMA GEMM, tile 128x128x64 (QKV, FC1). Same dbuf+swizzle.
// ---------------------------------------------------------------------------
__global__ __launch_bounds__(256) void gemm_mfma128(
    const __bf16* __restrict__ A, const __bf16* __restrict__ B,
    const float* __restrict__ bias, void* __restrict__ out,
    __bf16* __restrict__ vt_out, int M, int N, int K, int flags) {
    __shared__ __bf16 As[2][128][64];   // 32 KB
    __shared__ __bf16 Bs[2][128][64];   // 32 KB
    int tid = threadIdx.x, lane = tid & 63, wid = tid >> 6;
    int quad = lane >> 4, l16 = lane & 15;
    int wm = wid & 1, wn = wid >> 1;
    int m0 = blockIdx.y * 128, n0 = blockIdx.x * 128;
    int x7 = l16 & 7;

    auto stage = [&](int k0, int buf) {
        #pragma unroll
        for (int i = 0; i < 4; i++) {
            int c = i * 256 + tid;
            int row = c >> 3, cc = (c & 7) ^ (row & 7);
            int gm = m0 + row; if (gm > M - 1) gm = M - 1;
            gll16(A + (size_t)gm * K + k0 + cc * 8, &As[buf][0][0] + (size_t)c * 8);
        }
        #pragma unroll
        for (int i = 0; i < 4; i++) {
            int c = i * 256 + tid;
            int row = c >> 3, cc = (c & 7) ^ (row & 7);
            gll16(B + (size_t)(n0 + row) * K + k0 + cc * 8, &Bs[buf][0][0] + (size_t)c * 8);
        }
    };

    f32x4 acc[4][4] = {};
    int nk = K >> 6;
    stage(0, 0);
    __syncthreads();
    for (int ki = 0; ki < nk; ki++) {
        int cur = ki & 1;
        if (ki + 1 < nk) stage((ki + 1) << 6, cur ^ 1);
        #pragma unroll
        for (int s = 0; s < 2; s++) {
            bf16x8 a[4], b[4];
            #pragma unroll
            for (int i = 0; i < 4; i++)
                a[i] = *(bf16x8*)&As[cur][wm * 64 + i * 16 + l16][(((s * 4 + quad) ^ x7)) * 8];
            #pragma unroll
            for (int j = 0; j < 4; j++)
                b[j] = *(bf16x8*)&Bs[cur][wn * 64 + j * 16 + l16][(((s * 4 + quad) ^ x7)) * 8];
            #pragma unroll
            for (int i = 0; i < 4; i++)
                #pragma unroll
                for (int j = 0; j < 4; j++)
                    acc[i][j] = __builtin_amdgcn_mfma_f32_16x16x32_bf16(a[i], b[j], acc[i][j], 0, 0, 0);
        }
        __syncthreads();
    }

    #pragma unroll
    for (int j = 0; j < 4; j++) {
        int col = n0 + wn * 64 + j * 16 + l16;
        float bv = bias ? bias[col] : 0.f;
        #pragma unroll
        for (int i = 0; i < 4; i++) {
            int row0 = m0 + wm * 64 + i * 16 + quad * 4;
            if (row0 >= M) continue;
            float v4[4];
            #pragma unroll
            for (int r = 0; r < 4; r++) {
                float v = acc[i][j][r] + bv;
                if (flags & F_GELU) v = 0.5f * v * (1.f + erff(v * 0.70710678f));
                v4[r] = v;
            }
            if ((flags & F_QKV) && col >= 768) {
                int b2 = row0 / NTOK, n2 = row0 - b2 * NTOK;
                bf16x4 pk = { (__bf16)v4[0], (__bf16)v4[1], (__bf16)v4[2], (__bf16)v4[3] };
                *(bf16x4*)(vt_out + ((size_t)(b2 * DIM + (col - 768))) * NTOK + n2) = pk;
            } else {
                #pragma unroll
                for (int r = 0; r < 4; r++)
                    ((__bf16*)out)[(size_t)(row0 + r) * N + col] = (__bf16)v4[r];
            }
        }
    }
}

// ---------------------------------------------------------------------------
// Kernel 4: bf16 MFMA flash attention, 4 waves x 32 queries, dbuf K/V,
// XOR-swizzled staged tiles. Ps uses PADDED stride 72 (no xor): one base
// address + compile-time immediate offsets for all 32 ds_write_b16; both
// write (quad rows) and b128 read patterns are 2-way on banks (free).
// Split-K + in-kernel combine: last-arriving block (device-scope atomic)
// normalizes and writes O bf16.
// ---------------------------------------------------------------------------
__global__ __launch_bounds__(256) void attn_mfma(const __bf16* __restrict__ qkv,
                                                 const __bf16* __restrict__ vt,
                                                 float* __restrict__ opart,
                                                 float* __restrict__ lpart,
                                                 unsigned* __restrict__ cnt,
                                                 __bf16* __restrict__ o) {
    __shared__ __align__(16) char smemQP[128 * 72 * 2];   // 18 KB: Q staging, then Ps
    __shared__ __bf16 Ks[2][64][64];    // 16 KB
    __shared__ __bf16 Vt[2][64][64];    // 16 KB
    __shared__ unsigned old_s;
    __bf16 (*Qs)[64] = (__bf16(*)[64])smemQP;   // staging view [128][64]
    __bf16 (*Ps)[72] = (__bf16(*)[72])smemQP;   // P view [128][72]

    int tid = threadIdx.x, lane = tid & 63, wid = tid >> 6;
    int quad = lane >> 4, l16 = lane & 15;
    int q0 = blockIdx.x * 128;
    int bh = blockIdx.y;
    int ks = blockIdx.z;
    int b = bh / HEADS, h = bh % HEADS;
    int x7 = l16 & 7;
    const float cexp = 0.18033688f;   // (1/8) * log2(e)

    auto stageKV = [&](int k0, int buf) {
        #pragma unroll
        for (int i = 0; i < 2; i++) {
            int c = i * 256 + tid;
            int row = c >> 3, cc = (c & 7) ^ (row & 7);
            int gk = k0 + row; if (gk > NTOK - 1) gk = NTOK - 1;
            gll16(qkv + ((size_t)(b * NTOK + gk)) * 1152 + 384 + h * 64 + cc * 8,
                  &Ks[buf][0][0] + (size_t)c * 8);
            gll16(vt + ((size_t)(bh * 64 + row)) * NTOK + k0 + cc * 8,
                  &Vt[buf][0][0] + (size_t)c * 8);
        }
    };

    int kt0 = (43 * ks) / KSPLIT, kt1 = (43 * (ks + 1)) / KSPLIT;

    // stage Q (1024 chunks) + first K/V tile
    #pragma unroll
    for (int i = 0; i < 4; i++) {
        int c = i * 256 + tid;
        int row = c >> 3, cc = (c & 7) ^ (row & 7);
        int gq = q0 + row; if (gq > NTOK - 1) gq = NTOK - 1;
        gll16(qkv + ((size_t)(b * NTOK + gq)) * 1152 + h * 64 + cc * 8,
              &Qs[0][0] + (size_t)c * 8);
    }
    stageKV(kt0 * 64, 0);
    __syncthreads();

    // Q A-frags (wave band 32 rows = 2 q-subtiles) -> registers
    bf16x8 aq[2][2];
    #pragma unroll
    for (int qt = 0; qt < 2; qt++)
        #pragma unroll
        for (int s = 0; s < 2; s++)
            aq[qt][s] = *(bf16x8*)&Qs[wid * 32 + qt * 16 + l16][((s * 4 + quad) ^ x7) * 8];
    __syncthreads();   // Qs -> Ps overlay handoff

    f32x4 oacc[2][4] = {};
    float l_part[2][4] = {};
    __bf16* pwr = &Ps[wid * 32 + quad * 4][l16];          // write base
    const __bf16* prd = &Ps[wid * 32 + l16][0];            // read base

    for (int kt = kt0; kt < kt1; kt++) {
        int cur = (kt - kt0) & 1;
        if (kt + 1 < kt1) stageKV((kt + 1) * 64, cur ^ 1);
        int k0 = kt * 64;

        // S = Q K^T  (2 q-subtiles x 4 k-subtiles)
        f32x4 s[2][4];
        #pragma unroll
        for (int t = 0; t < 4; t++) {
            bf16x8 bk0 = *(bf16x8*)&Ks[cur][t * 16 + l16][((quad) ^ x7) * 8];
            bf16x8 bk1 = *(bf16x8*)&Ks[cur][t * 16 + l16][((4 + quad) ^ x7) * 8];
            #pragma unroll
            for (int qt = 0; qt < 2; qt++) {
                f32x4 z = {0.f, 0.f, 0.f, 0.f};
                z = __builtin_amdgcn_mfma_f32_16x16x32_bf16(aq[qt][0], bk0, z, 0, 0, 0);
                s[qt][t] = __builtin_amdgcn_mfma_f32_16x16x32_bf16(aq[qt][1], bk1, z, 0, 0, 0);
            }
        }
        if (k0 + 64 > NTOK) {   // mask invalid keys
            #pragma unroll
            for (int t = 0; t < 4; t++)
                if (k0 + t * 16 + l16 >= NTOK)
                    #pragma unroll
                    for (int qt = 0; qt < 2; qt++) {
                        s[qt][t][0] = -1e30f; s[qt][t][1] = -1e30f;
                        s[qt][t][2] = -1e30f; s[qt][t][3] = -1e30f;
                    }
        }
        // P = exp(S*scale) -> Ps (padded stride, imm-offset writes)
        #pragma unroll
        for (int qt = 0; qt < 2; qt++)
            #pragma unroll
            for (int t = 0; t < 4; t++)
                #pragma unroll
                for (int r = 0; r < 4; r++) {
                    float e = exp2f(s[qt][t][r] * cexp);
                    l_part[qt][r] += e;
                    pwr[(qt * 16 + r) * 72 + t * 16] = (__bf16)e;
                }
        // P A-frags (own band; intra-wave lgkm ordering)
        bf16x8 ap[2][2];
        #pragma unroll
        for (int qt = 0; qt < 2; qt++)
            #pragma unroll
            for (int sx = 0; sx < 2; sx++)
                ap[qt][sx] = *(bf16x8*)(prd + qt * 16 * 72 + sx * 32 + quad * 8);
        // O += P V
        #pragma unroll
        for (int t = 0; t < 4; t++) {
            bf16x8 bv0 = *(bf16x8*)&Vt[cur][t * 16 + l16][((quad) ^ x7) * 8];
            bf16x8 bv1 = *(bf16x8*)&Vt[cur][t * 16 + l16][((4 + quad) ^ x7) * 8];
            #pragma unroll
            for (int qt = 0; qt < 2; qt++) {
                oacc[qt][t] = __builtin_amdgcn_mfma_f32_16x16x32_bf16(ap[qt][0], bv0, oacc[qt][t], 0, 0, 0);
                oacc[qt][t] = __builtin_amdgcn_mfma_f32_16x16x32_bf16(ap[qt][1], bv1, oacc[qt][t], 0, 0, 0);
            }
        }
        __syncthreads();   // drains prefetch; all waves done with cur K/V
    }

    // store unnormalized partials
    #pragma unroll
    for (int qt = 0; qt < 2; qt++)
        #pragma unroll
        for (int r = 0; r < 4; r++) {
            int gq = q0 + wid * 32 + qt * 16 + quad * 4 + r;
            if (gq >= NTOK) continue;
            float l = l_part[qt][r];
            #pragma unroll
            for (int mk = 1; mk < 16; mk <<= 1) l += __shfl_xor(l, mk);
            if (l16 == 0) lpart[((size_t)ks * 12 + bh) * NTOK + gq] = l;
            float* op = opart + ((size_t)ks * MTOT + (size_t)b * NTOK + gq) * DIM + h * 64;
            #pragma unroll
            for (int t = 0; t < 4; t++) op[t * 16 + l16] = oacc[qt][t][r];
        }

    // split-K fixup: last block for (q0, bh) combines and writes O
    __threadfence();
    if (tid == 0)
        old_s = __hip_atomic_fetch_add(&cnt[blockIdx.x * 12 + bh], 1,
                                       __ATOMIC_ACQ_REL, __HIP_MEMORY_SCOPE_AGENT);
    __syncthreads();
    if (old_s == KSPLIT - 1) {
        __threadfence();
        // 128 q x 64 cols; thread handles 8 f32x4 groups
        #pragma unroll
        for (int i = 0; i < 8; i++) {
            int e = (i * 256 + tid) * 4;        // element in 128x64
            int qr = e >> 6, cc = e & 63;
            int gq = q0 + qr;
            if (gq >= NTOK) continue;
            f32x4 a = {0.f, 0.f, 0.f, 0.f};
            float l = 0.f;
            #pragma unroll
            for (int k2 = 0; k2 < KSPLIT; k2++) {
                f32x4 pv = *(const f32x4*)&opart[((size_t)k2 * MTOT + (size_t)b * NTOK + gq) * DIM + h * 64 + cc];
                a[0] += pv[0]; a[1] += pv[1]; a[2] += pv[2]; a[3] += pv[3];
                l += lpart[((size_t)k2 * 12 + bh) * NTOK + gq];
            }
            float inv = 1.f / l;
            bf16x4 ov = { (__bf16)(a[0] * inv), (__bf16)(a[1] * inv),
                          (__bf16)(a[2] * inv), (__bf16)(a[3] * inv) };
            *(bf16x4*)(o + ((size_t)(b * NTOK + gq)) * DIM + h * 64 + cc) = ov;
        }
    }
}

// ---------------------------------------------------------------------------
extern "C" void kernel_launch(void* const* d_in, const int* in_sizes, int n_in,
                              void* d_out, int out_size, void* d_ws, size_t ws_size,
                              hipStream_t stream) {
    const float* x      = (const float*)d_in[0];
    const float* conv_w = (const float*)d_in[1];
    // d_in[2] conv_b cancels in reference
    const float* ln1_w  = (const float*)d_in[3];
    const float* ln1_b  = (const float*)d_in[4];
    const float* qkv_w  = (const float*)d_in[5];
    const float* proj_w = (const float*)d_in[6];
    const float* proj_b = (const float*)d_in[7];
    const float* ln2_w  = (const float*)d_in[8];
    const float* ln2_b  = (const float*)d_in[9];
    const float* fc1_w  = (const float*)d_in[10];
    const float* fc1_b  = (const float*)d_in[11];
    const float* fc2_w  = (const float*)d_in[12];
    const float* fc2_b  = (const float*)d_in[13];
    float* out = (float*)d_out;

    char* p = (char*)d_ws;
    float*  T    = (float*)p;  p += (size_t)MTOT * DIM * 4;          //  8.4 MB
    __bf16* TN   = (__bf16*)p; p += (size_t)MTOT * DIM * 2;          //  4.2 MB
    __bf16* QKV  = (__bf16*)p; p += (size_t)MTOT * 1152 * 2;         // 12.6 MB
    __bf16* VT   = (__bf16*)p; p += (size_t)BATCH * DIM * NTOK * 2;  //  4.2 MB
    __bf16* O    = (__bf16*)p; p += (size_t)MTOT * DIM * 2;          //  4.2 MB
    __bf16* H    = (__bf16*)p; p += (size_t)MTOT * HIDDEN * 2;       // 16.9 MB
    __bf16* WQ   = (__bf16*)p; p += (size_t)1152 * 384 * 2;
    __bf16* WP   = (__bf16*)p; p += (size_t)384 * 384 * 2;
    __bf16* W1   = (__bf16*)p; p += (size_t)1536 * 384 * 2;
    __bf16* W2   = (__bf16*)p; p += (size_t)384 * 1536 * 2;
    float*  LP   = (float*)p;  p += (size_t)KSPLIT * 12 * NTOK * 4;
    unsigned* CNT = (unsigned*)p; p += (size_t)NQT * 12 * 4;
    float*  OP   = (float*)p;  p += (size_t)KSPLIT * MTOT * DIM * 4; // 25.3 MB
    // total ~80 MB

    // zero split-K counters (graph-capturable stream op)
    hipMemsetAsync(CNT, 0, (size_t)NQT * 12 * 4, stream);
    // 1. conv positional embedding + residual (fp32 trunk) + weight cvt
    conv_wcvt_kernel<<<8448 + 1728, 256, 0, stream>>>(
        x, conv_w, T, qkv_w, proj_w, fc1_w, fc2_w, WQ, WP, W1, W2);
    // 2. LN1 -> bf16
    ln_kernel<<<MTOT / 4, 256, 0, stream>>>(T, TN, ln1_w, ln1_b);
    // 3. QKV gemm (128x128): Q,K rows bf16; V -> VT transposed
    gemm_mfma128<<<dim3(9, 43), 256, 0, stream>>>(
        TN, WQ, nullptr, QKV, VT, MTOT, 1152, 384, F_QKV);
    // 4. attention (split-K partials + in-kernel combine) -> O bf16
    attn_mfma<<<dim3(NQT, 12, KSPLIT), 256, 0, stream>>>(QKV, VT, OP, LP, CNT, O);
    // 5. T += O @ proj_w^T + proj_b (fp32 trunk)
    gemm_mfma<<<dim3(6, 43), 256, 0, stream>>>(
        O, WP, proj_b, T, T, MTOT, 384, 384, F_RESID);
    // 6. LN2 -> bf16
    ln_kernel<<<MTOT / 4, 256, 0, stream>>>(T, TN, ln2_w, ln2_b);
    // 7. H = gelu(TN @ fc1_w^T + fc1_b) bf16 (128x128)
    gemm_mfma128<<<dim3(12, 43), 256, 0, stream>>>(
        TN, W1, fc1_b, H, nullptr, MTOT, 1536, 384, F_GELU | F_BF16);
    // 8. out[b,c,n] = T + H @ fc2_w^T + fc2_b (fp32, transposed store)
    gemm_mfma<<<dim3(6, 43), 256, 0, stream>>>(
        H, W2, fc2_b, T, out, MTOT, 384, 1536, F_RESID | F_TRANS);
}

// Round 7
// 300.191 us; speedup vs baseline: 1.5164x; 1.5164x over previous
//
#include <hip/hip_runtime.h>
#include <hip/hip_bf16.h>
#include <math.h>

#define DIM 384
#define HEADS 6
#define HIDDEN 1536
#define NTOK 2744   // 14*14*14
#define BATCH 2
#define MTOT (BATCH * NTOK)   // 5488
#define KSPLIT 3
#define NQT 22      // ceil(2744/128)

typedef __bf16 bf16x8 __attribute__((ext_vector_type(8)));
typedef __bf16 bf16x4 __attribute__((ext_vector_type(4)));
typedef float  f32x4  __attribute__((ext_vector_type(4)));

// async global->LDS, 16B per lane; LDS dest = uniform base + lane*16
__device__ __forceinline__ void gll16(const void* g, void* l) {
    __builtin_amdgcn_global_load_lds(
        (const __attribute__((address_space(1))) unsigned int*)g,
        (__attribute__((address_space(3))) unsigned int*)l, 16, 0, 0);
}

// ---------------------------------------------------------------------------
// Kernel 1: fused depthwise conv3d (+residual, NCDHW -> t[token,C] fp32)
// and weight fp32->bf16 conversion (tail blocks).
// ---------------------------------------------------------------------------
__global__ void conv_wcvt_kernel(const float* __restrict__ x,
                                 const float* __restrict__ cw,
                                 float* __restrict__ t,
                                 const float* __restrict__ w0, const float* __restrict__ w1,
                                 const float* __restrict__ w2, const float* __restrict__ w3,
                                 __bf16* o0, __bf16* o1, __bf16* o2, __bf16* o3) {
    int bid = blockIdx.x;
    if (bid >= 8448) {   // ---- weight conversion ----
        int i = (bid - 8448) * 256 + threadIdx.x;   // float4 index
        const float* s; __bf16* d; int off;
        if (i < 110592)      { s = w0; d = o0; off = i; }
        else if (i < 147456) { s = w1; d = o1; off = i - 110592; }
        else if (i < 294912) { s = w2; d = o2; off = i - 147456; }
        else                 { s = w3; d = o3; off = i - 294912; }
        float4 v = ((const float4*)s)[off];
        bf16x4 bb = { (__bf16)v.x, (__bf16)v.y, (__bf16)v.z, (__bf16)v.w };
        *(bf16x4*)(d + (size_t)off * 4) = bb;
        return;
    }
    // ---- conv ----
    int nb = bid % 11, rest = bid / 11;
    int c = rest % 384, b = rest / 384;
    int n = nb * 256 + threadIdx.x;
    if (n >= NTOK) return;
    int d = n / 196, r = n % 196, h = r / 14, w = r % 14;
    const float* xp = x + ((size_t)b * DIM + c) * NTOK;
    const float* wp = cw + c * 27;
    float acc = xp[n];   // residual (conv_b cancels in reference)
    #pragma unroll
    for (int kd = 0; kd < 3; kd++) {
        int dd = d + kd - 1;
        if (dd < 0 || dd >= 14) continue;
        #pragma unroll
        for (int kh = 0; kh < 3; kh++) {
            int hh = h + kh - 1;
            if (hh < 0 || hh >= 14) continue;
            #pragma unroll
            for (int kw = 0; kw < 3; kw++) {
                int ww = w + kw - 1;
                if (ww < 0 || ww >= 14) continue;
                acc += wp[kd * 9 + kh * 3 + kw] * xp[(dd * 14 + hh) * 14 + ww];
            }
        }
    }
    t[((size_t)(b * NTOK + n)) * DIM + c] = acc;
}

// ---------------------------------------------------------------------------
// Kernel 2: LayerNorm fp32 in -> bf16 out. One wave per token.
// ---------------------------------------------------------------------------
__global__ void ln_kernel(const float* __restrict__ in, __bf16* __restrict__ out,
                          const float* __restrict__ w, const float* __restrict__ b) {
    int wid = threadIdx.x >> 6, lane = threadIdx.x & 63;
    int token = blockIdx.x * 4 + wid;
    const float* row = in + (size_t)token * DIM;
    float v[6];
    float s = 0.f, s2 = 0.f;
    #pragma unroll
    for (int i = 0; i < 6; i++) {
        v[i] = row[lane + 64 * i];
        s += v[i];
        s2 += v[i] * v[i];
    }
    #pragma unroll
    for (int m = 1; m < 64; m <<= 1) {
        s += __shfl_xor(s, m);
        s2 += __shfl_xor(s2, m);
    }
    float mu = s * (1.f / DIM);
    float var = s2 * (1.f / DIM) - mu * mu;
    float rstd = rsqrtf(var + 1e-5f);
    __bf16* orow = out + (size_t)token * DIM;
    #pragma unroll
    for (int i = 0; i < 6; i++) {
        int c = lane + 64 * i;
        orow[c] = (__bf16)((v[i] - mu) * rstd * w[c] + b[c]);
    }
}

#define F_GELU  1
#define F_RESID 2
#define F_BF16  4
#define F_QKV   8
#define F_TRANS 16

// ---------------------------------------------------------------------------
// Kernel 3a: bf16 MFMA GEMM, tile 128x64x64 (proj, fc2). Dbuf async staging
// + XOR chunk swizzle (bank-optimal b128 frag reads).
// ---------------------------------------------------------------------------
__global__ __launch_bounds__(256) void gemm_mfma(
    const __bf16* __restrict__ A, const __bf16* __restrict__ B,
    const float* __restrict__ bias, const float* __restrict__ resid,
    void* __restrict__ out, int M, int N, int K, int flags) {
    __shared__ __bf16 As[2][128][64];   // 32 KB
    __shared__ __bf16 Bs[2][64][64];    // 16 KB
    int tid = threadIdx.x, lane = tid & 63;
    int wid = tid >> 6;
    int quad = lane >> 4, l16 = lane & 15;
    int wm = wid & 1, wn = wid >> 1;
    int m0 = blockIdx.y * 128, n0 = blockIdx.x * 64;
    int x7 = l16 & 7;

    auto stage = [&](int k0, int buf) {
        #pragma unroll
        for (int i = 0; i < 4; i++) {
            int c = i * 256 + tid;
            int row = c >> 3, cc = (c & 7) ^ (row & 7);
            int gm = m0 + row; if (gm > M - 1) gm = M - 1;
            gll16(A + (size_t)gm * K + k0 + cc * 8, &As[buf][0][0] + (size_t)c * 8);
        }
        #pragma unroll
        for (int i = 0; i < 2; i++) {
            int c = i * 256 + tid;
            int row = c >> 3, cc = (c & 7) ^ (row & 7);
            gll16(B + (size_t)(n0 + row) * K + k0 + cc * 8, &Bs[buf][0][0] + (size_t)c * 8);
        }
    };

    f32x4 acc[4][2] = {};
    int nk = K >> 6;
    stage(0, 0);
    __syncthreads();
    for (int ki = 0; ki < nk; ki++) {
        int cur = ki & 1;
        if (ki + 1 < nk) stage((ki + 1) << 6, cur ^ 1);
        #pragma unroll
        for (int s = 0; s < 2; s++) {
            bf16x8 a[4], b[2];
            #pragma unroll
            for (int i = 0; i < 4; i++)
                a[i] = *(bf16x8*)&As[cur][wm * 64 + i * 16 + l16][(((s * 4 + quad) ^ x7)) * 8];
            #pragma unroll
            for (int j = 0; j < 2; j++)
                b[j] = *(bf16x8*)&Bs[cur][wn * 32 + j * 16 + l16][(((s * 4 + quad) ^ x7)) * 8];
            #pragma unroll
            for (int i = 0; i < 4; i++)
                #pragma unroll
                for (int j = 0; j < 2; j++)
                    acc[i][j] = __builtin_amdgcn_mfma_f32_16x16x32_bf16(a[i], b[j], acc[i][j], 0, 0, 0);
        }
        __syncthreads();
    }

    int colb = n0 + wn * 32;
    #pragma unroll
    for (int j = 0; j < 2; j++) {
        int col = colb + j * 16 + l16;
        float bv = bias ? bias[col] : 0.f;
        #pragma unroll
        for (int i = 0; i < 4; i++) {
            int row0 = m0 + wm * 64 + i * 16 + quad * 4;
            if (row0 >= M) continue;
            float v4[4];
            #pragma unroll
            for (int r = 0; r < 4; r++) {
                float v = acc[i][j][r] + bv;
                if (flags & F_GELU) v = 0.5f * v * (1.f + erff(v * 0.70710678f));
                if (flags & F_RESID) v += resid[(size_t)(row0 + r) * N + col];
                v4[r] = v;
            }
            if (flags & F_TRANS) {
                int b2 = row0 / NTOK, n2 = row0 - b2 * NTOK;
                float4 pk = { v4[0], v4[1], v4[2], v4[3] };
                *(float4*)((float*)out + ((size_t)(b2 * N + col)) * NTOK + n2) = pk;
            } else if (flags & F_BF16) {
                #pragma unroll
                for (int r = 0; r < 4; r++)
                    ((__bf16*)out)[(size_t)(row0 + r) * N + col] = (__bf16)v4[r];
            } else {
                #pragma unroll
                for (int r = 0; r < 4; r++)
                    ((float*)out)[(size_t)(row0 + r) * N + col] = v4[r];
            }
        }
    }
}

// ---------------------------------------------------------------------------
// Kernel 3b: bf16 MFMA GEMM, tile 128x128x64 (QKV, FC1). Same dbuf+swizzle.
// ---------------------------------------------------------------------------
__global__ __launch_bounds__(256) void gemm_mfma128(
    const __bf16* __restrict__ A, const __bf16* __restrict__ B,
    const float* __restrict__ bias, void* __restrict__ out,
    __bf16* __restrict__ vt_out, int M, int N, int K, int flags) {
    __shared__ __bf16 As[2][128][64];   // 32 KB
    __shared__ __bf16 Bs[2][128][64];   // 32 KB
    int tid = threadIdx.x, lane = tid & 63, wid = tid >> 6;
    int quad = lane >> 4, l16 = lane & 15;
    int wm = wid & 1, wn = wid >> 1;
    int m0 = blockIdx.y * 128, n0 = blockIdx.x * 128;
    int x7 = l16 & 7;

    auto stage = [&](int k0, int buf) {
        #pragma unroll
        for (int i = 0; i < 4; i++) {
            int c = i * 256 + tid;
            int row = c >> 3, cc = (c & 7) ^ (row & 7);
            int gm = m0 + row; if (gm > M - 1) gm = M - 1;
            gll16(A + (size_t)gm * K + k0 + cc * 8, &As[buf][0][0] + (size_t)c * 8);
        }
        #pragma unroll
        for (int i = 0; i < 4; i++) {
            int c = i * 256 + tid;
            int row = c >> 3, cc = (c & 7) ^ (row & 7);
            gll16(B + (size_t)(n0 + row) * K + k0 + cc * 8, &Bs[buf][0][0] + (size_t)c * 8);
        }
    };

    f32x4 acc[4][4] = {};
    int nk = K >> 6;
    stage(0, 0);
    __syncthreads();
    for (int ki = 0; ki < nk; ki++) {
        int cur = ki & 1;
        if (ki + 1 < nk) stage((ki + 1) << 6, cur ^ 1);
        #pragma unroll
        for (int s = 0; s < 2; s++) {
            bf16x8 a[4], b[4];
            #pragma unroll
            for (int i = 0; i < 4; i++)
                a[i] = *(bf16x8*)&As[cur][wm * 64 + i * 16 + l16][(((s * 4 + quad) ^ x7)) * 8];
            #pragma unroll
            for (int j = 0; j < 4; j++)
                b[j] = *(bf16x8*)&Bs[cur][wn * 64 + j * 16 + l16][(((s * 4 + quad) ^ x7)) * 8];
            #pragma unroll
            for (int i = 0; i < 4; i++)
                #pragma unroll
                for (int j = 0; j < 4; j++)
                    acc[i][j] = __builtin_amdgcn_mfma_f32_16x16x32_bf16(a[i], b[j], acc[i][j], 0, 0, 0);
        }
        __syncthreads();
    }

    #pragma unroll
    for (int j = 0; j < 4; j++) {
        int col = n0 + wn * 64 + j * 16 + l16;
        float bv = bias ? bias[col] : 0.f;
        #pragma unroll
        for (int i = 0; i < 4; i++) {
            int row0 = m0 + wm * 64 + i * 16 + quad * 4;
            if (row0 >= M) continue;
            float v4[4];
            #pragma unroll
            for (int r = 0; r < 4; r++) {
                float v = acc[i][j][r] + bv;
                if (flags & F_GELU) v = 0.5f * v * (1.f + erff(v * 0.70710678f));
                v4[r] = v;
            }
            if ((flags & F_QKV) && col >= 768) {
                int b2 = row0 / NTOK, n2 = row0 - b2 * NTOK;
                bf16x4 pk = { (__bf16)v4[0], (__bf16)v4[1], (__bf16)v4[2], (__bf16)v4[3] };
                *(bf16x4*)(vt_out + ((size_t)(b2 * DIM + (col - 768))) * NTOK + n2) = pk;
            } else {
                #pragma unroll
                for (int r = 0; r < 4; r++)
                    ((__bf16*)out)[(size_t)(row0 + r) * N + col] = (__bf16)v4[r];
            }
        }
    }
}

// ---------------------------------------------------------------------------
// Kernel 4: bf16 MFMA flash attention, 4 waves x 32 queries, dbuf K/V,
// XOR-swizzled staged tiles. Ps uses PADDED stride 72 (no xor): one base
// address + compile-time immediate offsets for all 32 ds_write_b16; both
// writes (quad rows) and b128 frag reads are <=2-way on banks (free).
// Unnormalized exp + split-K; separate combine kernel (NO device-scope
// fences here — R6 showed per-block L2 writeback costs 3x the kernel).
// ---------------------------------------------------------------------------
__global__ __launch_bounds__(256) void attn_mfma(const __bf16* __restrict__ qkv,
                                                 const __bf16* __restrict__ vt,
                                                 float* __restrict__ opart,
                                                 float* __restrict__ lpart) {
    __shared__ __align__(16) char smemQP[128 * 72 * 2];   // 18 KB: Q staging, then Ps
    __shared__ __bf16 Ks[2][64][64];    // 16 KB
    __shared__ __bf16 Vt[2][64][64];    // 16 KB
    __bf16 (*Qs)[64] = (__bf16(*)[64])smemQP;   // staging view [128][64]
    __bf16 (*Ps)[72] = (__bf16(*)[72])smemQP;   // P view [128][72]

    int tid = threadIdx.x, lane = tid & 63, wid = tid >> 6;
    int quad = lane >> 4, l16 = lane & 15;
    int q0 = blockIdx.x * 128;
    int bh = blockIdx.y;
    int ks = blockIdx.z;
    int b = bh / HEADS, h = bh % HEADS;
    int x7 = l16 & 7;
    const float cexp = 0.18033688f;   // (1/8) * log2(e)

    auto stageKV = [&](int k0, int buf) {
        #pragma unroll
        for (int i = 0; i < 2; i++) {
            int c = i * 256 + tid;
            int row = c >> 3, cc = (c & 7) ^ (row & 7);
            int gk = k0 + row; if (gk > NTOK - 1) gk = NTOK - 1;
            gll16(qkv + ((size_t)(b * NTOK + gk)) * 1152 + 384 + h * 64 + cc * 8,
                  &Ks[buf][0][0] + (size_t)c * 8);
            gll16(vt + ((size_t)(bh * 64 + row)) * NTOK + k0 + cc * 8,
                  &Vt[buf][0][0] + (size_t)c * 8);
        }
    };

    int kt0 = (43 * ks) / KSPLIT, kt1 = (43 * (ks + 1)) / KSPLIT;

    // stage Q (1024 chunks) + first K/V tile
    #pragma unroll
    for (int i = 0; i < 4; i++) {
        int c = i * 256 + tid;
        int row = c >> 3, cc = (c & 7) ^ (row & 7);
        int gq = q0 + row; if (gq > NTOK - 1) gq = NTOK - 1;
        gll16(qkv + ((size_t)(b * NTOK + gq)) * 1152 + h * 64 + cc * 8,
              &Qs[0][0] + (size_t)c * 8);
    }
    stageKV(kt0 * 64, 0);
    __syncthreads();

    // Q A-frags (wave band 32 rows = 2 q-subtiles) -> registers
    bf16x8 aq[2][2];
    #pragma unroll
    for (int qt = 0; qt < 2; qt++)
        #pragma unroll
        for (int s = 0; s < 2; s++)
            aq[qt][s] = *(bf16x8*)&Qs[wid * 32 + qt * 16 + l16][((s * 4 + quad) ^ x7) * 8];
    __syncthreads();   // Qs -> Ps overlay handoff

    f32x4 oacc[2][4] = {};
    float l_part[2][4] = {};
    __bf16* pwr = &Ps[wid * 32 + quad * 4][l16];          // write base
    const __bf16* prd = &Ps[wid * 32 + l16][0];           // read base

    for (int kt = kt0; kt < kt1; kt++) {
        int cur = (kt - kt0) & 1;
        if (kt + 1 < kt1) stageKV((kt + 1) * 64, cur ^ 1);
        int k0 = kt * 64;

        // S = Q K^T  (2 q-subtiles x 4 k-subtiles)
        f32x4 s[2][4];
        #pragma unroll
        for (int t = 0; t < 4; t++) {
            bf16x8 bk0 = *(bf16x8*)&Ks[cur][t * 16 + l16][((quad) ^ x7) * 8];
            bf16x8 bk1 = *(bf16x8*)&Ks[cur][t * 16 + l16][((4 + quad) ^ x7) * 8];
            #pragma unroll
            for (int qt = 0; qt < 2; qt++) {
                f32x4 z = {0.f, 0.f, 0.f, 0.f};
                z = __builtin_amdgcn_mfma_f32_16x16x32_bf16(aq[qt][0], bk0, z, 0, 0, 0);
                s[qt][t] = __builtin_amdgcn_mfma_f32_16x16x32_bf16(aq[qt][1], bk1, z, 0, 0, 0);
            }
        }
        if (k0 + 64 > NTOK) {   // mask invalid keys
            #pragma unroll
            for (int t = 0; t < 4; t++)
                if (k0 + t * 16 + l16 >= NTOK)
                    #pragma unroll
                    for (int qt = 0; qt < 2; qt++) {
                        s[qt][t][0] = -1e30f; s[qt][t][1] = -1e30f;
                        s[qt][t][2] = -1e30f; s[qt][t][3] = -1e30f;
                    }
        }
        // P = exp(S*scale) -> Ps (padded stride, imm-offset writes)
        #pragma unroll
        for (int qt = 0; qt < 2; qt++)
            #pragma unroll
            for (int t = 0; t < 4; t++)
                #pragma unroll
                for (int r = 0; r < 4; r++) {
                    float e = exp2f(s[qt][t][r] * cexp);
                    l_part[qt][r] += e;
                    pwr[(qt * 16 + r) * 72 + t * 16] = (__bf16)e;
                }
        // P A-frags (own band; intra-wave lgkm ordering)
        bf16x8 ap[2][2];
        #pragma unroll
        for (int qt = 0; qt < 2; qt++)
            #pragma unroll
            for (int sx = 0; sx < 2; sx++)
                ap[qt][sx] = *(bf16x8*)(prd + qt * 16 * 72 + sx * 32 + quad * 8);
        // O += P V
        #pragma unroll
        for (int t = 0; t < 4; t++) {
            bf16x8 bv0 = *(bf16x8*)&Vt[cur][t * 16 + l16][((quad) ^ x7) * 8];
            bf16x8 bv1 = *(bf16x8*)&Vt[cur][t * 16 + l16][((4 + quad) ^ x7) * 8];
            #pragma unroll
            for (int qt = 0; qt < 2; qt++) {
                oacc[qt][t] = __builtin_amdgcn_mfma_f32_16x16x32_bf16(ap[qt][0], bv0, oacc[qt][t], 0, 0, 0);
                oacc[qt][t] = __builtin_amdgcn_mfma_f32_16x16x32_bf16(ap[qt][1], bv1, oacc[qt][t], 0, 0, 0);
            }
        }
        __syncthreads();   // drains prefetch; all waves done with cur K/V
    }

    // store unnormalized partials
    #pragma unroll
    for (int qt = 0; qt < 2; qt++)
        #pragma unroll
        for (int r = 0; r < 4; r++) {
            int gq = q0 + wid * 32 + qt * 16 + quad * 4 + r;
            if (gq >= NTOK) continue;
            float l = l_part[qt][r];
            #pragma unroll
            for (int mk = 1; mk < 16; mk <<= 1) l += __shfl_xor(l, mk);
            if (l16 == 0) lpart[((size_t)ks * 12 + bh) * NTOK + gq] = l;
            float* op = opart + ((size_t)ks * MTOT + (size_t)b * NTOK + gq) * DIM + h * 64;
            #pragma unroll
            for (int t = 0; t < 4; t++) op[t * 16 + l16] = oacc[qt][t][r];
        }
}

// ---------------------------------------------------------------------------
// Kernel 5: combine split-K partials -> O bf16.
// ---------------------------------------------------------------------------
__global__ void attn_combine(const float* __restrict__ opart,
                             const float* __restrict__ lpart,
                             __bf16* __restrict__ o) {
    int idx = blockIdx.x * 256 + threadIdx.x;   // MTOT*96 total
    int token = idx / 96, rem = idx - token * 96;
    int c = rem * 4, h = c >> 6;
    int b2 = token / NTOK, n = token - b2 * NTOK;
    int bh = b2 * HEADS + h;
    f32x4 acc = {0.f, 0.f, 0.f, 0.f};
    float l = 0.f;
    #pragma unroll
    for (int ks = 0; ks < KSPLIT; ks++) {
        f32x4 p = *(const f32x4*)&opart[((size_t)ks * MTOT + token) * DIM + c];
        acc[0] += p[0]; acc[1] += p[1]; acc[2] += p[2]; acc[3] += p[3];
        l += lpart[((size_t)ks * 12 + bh) * NTOK + n];
    }
    float inv = 1.f / l;
    bf16x4 ov = { (__bf16)(acc[0] * inv), (__bf16)(acc[1] * inv),
                  (__bf16)(acc[2] * inv), (__bf16)(acc[3] * inv) };
    *(bf16x4*)(o + (size_t)token * DIM + c) = ov;
}

// ---------------------------------------------------------------------------
extern "C" void kernel_launch(void* const* d_in, const int* in_sizes, int n_in,
                              void* d_out, int out_size, void* d_ws, size_t ws_size,
                              hipStream_t stream) {
    const float* x      = (const float*)d_in[0];
    const float* conv_w = (const float*)d_in[1];
    // d_in[2] conv_b cancels in reference
    const float* ln1_w  = (const float*)d_in[3];
    const float* ln1_b  = (const float*)d_in[4];
    const float* qkv_w  = (const float*)d_in[5];
    const float* proj_w = (const float*)d_in[6];
    const float* proj_b = (const float*)d_in[7];
    const float* ln2_w  = (const float*)d_in[8];
    const float* ln2_b  = (const float*)d_in[9];
    const float* fc1_w  = (const float*)d_in[10];
    const float* fc1_b  = (const float*)d_in[11];
    const float* fc2_w  = (const float*)d_in[12];
    const float* fc2_b  = (const float*)d_in[13];
    float* out = (float*)d_out;

    char* p = (char*)d_ws;
    float*  T    = (float*)p;  p += (size_t)MTOT * DIM * 4;          //  8.4 MB
    __bf16* TN   = (__bf16*)p; p += (size_t)MTOT * DIM * 2;          //  4.2 MB
    __bf16* QKV  = (__bf16*)p; p += (size_t)MTOT * 1152 * 2;         // 12.6 MB
    __bf16* VT   = (__bf16*)p; p += (size_t)BATCH * DIM * NTOK * 2;  //  4.2 MB
    __bf16* O    = (__bf16*)p; p += (size_t)MTOT * DIM * 2;          //  4.2 MB
    __bf16* H    = (__bf16*)p; p += (size_t)MTOT * HIDDEN * 2;       // 16.9 MB
    __bf16* WQ   = (__bf16*)p; p += (size_t)1152 * 384 * 2;
    __bf16* WP   = (__bf16*)p; p += (size_t)384 * 384 * 2;
    __bf16* W1   = (__bf16*)p; p += (size_t)1536 * 384 * 2;
    __bf16* W2   = (__bf16*)p; p += (size_t)384 * 1536 * 2;
    float*  LP   = (float*)p;  p += (size_t)KSPLIT * 12 * NTOK * 4;
    float*  OP   = (float*)p;  p += (size_t)KSPLIT * MTOT * DIM * 4; // 25.3 MB
    // total ~80 MB

    // 1. conv positional embedding + residual (fp32 trunk) + weight cvt
    conv_wcvt_kernel<<<8448 + 1728, 256, 0, stream>>>(
        x, conv_w, T, qkv_w, proj_w, fc1_w, fc2_w, WQ, WP, W1, W2);
    // 2. LN1 -> bf16
    ln_kernel<<<MTOT / 4, 256, 0, stream>>>(T, TN, ln1_w, ln1_b);
    // 3. QKV gemm (128x128): Q,K rows bf16; V -> VT transposed
    gemm_mfma128<<<dim3(9, 43), 256, 0, stream>>>(
        TN, WQ, nullptr, QKV, VT, MTOT, 1152, 384, F_QKV);
    // 4. attention partials + combine -> O bf16
    attn_mfma<<<dim3(NQT, 12, KSPLIT), 256, 0, stream>>>(QKV, VT, OP, LP);
    attn_combine<<<(MTOT * 96) / 256, 256, 0, stream>>>(OP, LP, O);
    // 5. T += O @ proj_w^T + proj_b (fp32 trunk)
    gemm_mfma<<<dim3(6, 43), 256, 0, stream>>>(
        O, WP, proj_b, T, T, MTOT, 384, 384, F_RESID);
    // 6. LN2 -> bf16
    ln_kernel<<<MTOT / 4, 256, 0, stream>>>(T, TN, ln2_w, ln2_b);
    // 7. H = gelu(TN @ fc1_w^T + fc1_b) bf16 (128x128)
    gemm_mfma128<<<dim3(12, 43), 256, 0, stream>>>(
        TN, W1, fc1_b, H, nullptr, MTOT, 1536, 384, F_GELU | F_BF16);
    // 8. out[b,c,n] = T + H @ fc2_w^T + fc2_b (fp32, transposed store)
    gemm_mfma<<<dim3(6, 43), 256, 0, stream>>>(
        H, W2, fc2_b, T, out, MTOT, 384, 1536, F_RESID | F_TRANS);
}